// Round 4
// baseline (33.828 us; speedup 1.0000x reference)
//
#include <hip/hip_runtime.h>

// MaxIndexLinearTraining: per-group (q=4) softmax then weighted sum with [1,2,3,4].
// Input: (4096, 8192) f32 -> 8,388,608 groups of 4 consecutive floats.
// Output: 8,388,608 f32.
// Memory-bound: 16B read + 4B write per group. Roofline ~26.6 us @ 6.3 TB/s copy BW.
// R1 (grid-stride, plain ld/st): 28.76 us (5.83 TB/s). R2 (unroll+NT store): 29.69 -> reverted.
// R3: nontemporal builtin needs a native vector type, not HIP_vector_type -> fixed in R4.

typedef float fvec4 __attribute__((ext_vector_type(4)));

__global__ __launch_bounds__(256) void soft_argmax_q4_kernel(
    const fvec4* __restrict__ in,
    float* __restrict__ out,
    int n_groups)
{
    int g = blockIdx.x * blockDim.x + threadIdx.x;
    if (g >= n_groups) return;

    // Input is read exactly once across the whole kernel: stream it (nt).
    fvec4 v = __builtin_nontemporal_load(&in[g]);

    float m  = fmaxf(fmaxf(v.x, v.y), fmaxf(v.z, v.w));
    float e0 = __expf(v.x - m);
    float e1 = __expf(v.y - m);
    float e2 = __expf(v.z - m);
    float e3 = __expf(v.w - m);
    float denom = e0 + e1 + e2 + e3;
    float num   = fmaf(4.f, e3, fmaf(3.f, e2, fmaf(2.f, e1, e0)));
    out[g] = num / denom;
}

extern "C" void kernel_launch(void* const* d_in, const int* in_sizes, int n_in,
                              void* d_out, int out_size, void* d_ws, size_t ws_size,
                              hipStream_t stream) {
    (void)n_in; (void)d_ws; (void)ws_size;
    const fvec4* in = (const fvec4*)d_in[0];
    float* out = (float*)d_out;

    const int n_groups = out_size;                  // 8,388,608 = 32768 * 256
    const int block = 256;
    const int grid  = (n_groups + block - 1) / block;  // exact cover, no loop

    soft_argmax_q4_kernel<<<grid, block, 0, stream>>>(in, out, n_groups);
}

// Round 5
// 29.171 us; speedup vs baseline: 1.1596x; 1.1596x over previous
//
#include <hip/hip_runtime.h>

// MaxIndexLinearTraining: per-group (q=4) softmax then weighted sum with [1,2,3,4].
// Input: (4096, 8192) f32 -> 8,388,608 groups of 4 consecutive floats.
// Output: 8,388,608 f32.
// Memory-bound: 16B read + 4B write per group (160 MiB total, L3-resident across replays).
// Ledger: R1 grid-stride plain = 28.76 us (5.83 TB/s)  <- best
//         R2 unroll x2 + NT store = 29.69 us (reverted)
//         R4 exact-cover + NT load = 33.83 us (NT defeats L3 residency; reverted)
// This is R1 restored.

__global__ __launch_bounds__(256) void soft_argmax_q4_kernel(
    const float4* __restrict__ in,   // one float4 per group
    float* __restrict__ out,
    int n_groups)
{
    int idx    = blockIdx.x * blockDim.x + threadIdx.x;
    int stride = gridDim.x * blockDim.x;
    for (int g = idx; g < n_groups; g += stride) {
        float4 v = in[g];
        float m  = fmaxf(fmaxf(v.x, v.y), fmaxf(v.z, v.w));
        float e0 = __expf(v.x - m);
        float e1 = __expf(v.y - m);
        float e2 = __expf(v.z - m);
        float e3 = __expf(v.w - m);
        float denom = e0 + e1 + e2 + e3;
        float num   = fmaf(4.f, e3, fmaf(3.f, e2, fmaf(2.f, e1, e0)));
        out[g] = num / denom;
    }
}

extern "C" void kernel_launch(void* const* d_in, const int* in_sizes, int n_in,
                              void* d_out, int out_size, void* d_ws, size_t ws_size,
                              hipStream_t stream) {
    (void)n_in; (void)d_ws; (void)ws_size;
    const float4* in = (const float4*)d_in[0];
    float* out = (float*)d_out;

    const int n_groups = out_size;                 // 8,388,608
    const int block = 256;
    int grid = (n_groups + block - 1) / block;
    if (grid > 4096) grid = 4096;                  // grid-stride: 8 groups/thread

    soft_argmax_q4_kernel<<<grid, block, 0, stream>>>(in, out, n_groups);
}